// Round 13
// baseline (388.731 us; speedup 1.0000x reference)
//
#include <hip/hip_runtime.h>
#include <math.h>

// LSTM B=1024,T=512,IN=16,H=64,OUT=8, gates i,f,g,o.
// R13: 2-STAGE SOFTWARE PIPELINE. R9/R11/R12 all plateau ~1120-1160
// cyc/step because one round contains a full step: read->MFMA->act->write->
// barrier (chain legs + issue serialize). Now each step spans 2 rounds:
//   round r: [MFMA stage, stream X: ds_read h_{t-1} + 8 h-MFMA -> acc,
//             consumed NEXT round -> no wait at round end]
//          + [ACT stage, stream Y: act(acc from last round) -> c,h ->
//             ds_write + 4 x-MFMA re-init acc with bias+W_ih.x]
// Streams = 2 batch-pairs (BT=4: {0,1},{2,3}), phase-offset 1 round.
// ds_read latency hides under act trans; MFMA pipe results have a full
// round of slack. 1024 rounds x ~350-420 cyc vs 512 x 1120.
// Grid 256 blocks (1/CU) x 256 thr. Per-stream lane map as R11: cols =
// 2 batches x 8 replicas (b=m&1, rho=(m>>1)&3, writers m<8), wave w owns
// j-slice [16w,16w+16), tiles tt = gate type, fp16 weights (log2e folded)
// pinned in regs, hbuf dbuf stride 72 halves, lite barrier per round.

#define LSTM_T 512
#define LSTM_IN 16
#define LSTM_H 64
#define LSTM_OUT 8
#define BT 4
#define HSTRIDE 72         // halves per batch row: 64 h + 8 pad (bank spread)

#define L2E   1.44269504088896340736f
#define L2E2  2.88539008177792681472f

typedef _Float16 half8  __attribute__((ext_vector_type(8)));
typedef float    floatx4 __attribute__((ext_vector_type(4)));

static __device__ __forceinline__ float fast_rcp(float x) { return __builtin_amdgcn_rcpf(x); }
static __device__ __forceinline__ float fast_exp2(float x) { return __builtin_amdgcn_exp2f(x); }
static __device__ __forceinline__ float sigm2(float p) { return fast_rcp(1.0f + fast_exp2(-p)); }
static __device__ __forceinline__ float tanh2(float p) {
    return fmaf(-2.0f, fast_rcp(1.0f + fast_exp2(p)), 1.0f);
}
static __device__ __forceinline__ void pin4(int4& v) {
    asm volatile("" : "+v"(v.x), "+v"(v.y), "+v"(v.z), "+v"(v.w));
}
static __device__ __forceinline__ void pinf4(float4& v) {
    asm volatile("" : "+v"(v.x), "+v"(v.y), "+v"(v.z), "+v"(v.w));
}
static __device__ __forceinline__ void lite_barrier() {
    asm volatile("s_waitcnt lgkmcnt(0)\n\ts_barrier" ::: "memory");
}
static __device__ __forceinline__ unsigned pk2h(float a, float b) {
    return __builtin_bit_cast(unsigned, __builtin_amdgcn_cvt_pkrtz(a, b));
}
static __device__ __forceinline__ half8 to_h8(float4 a, float4 b) {
    uint4 u = make_uint4(pk2h(a.x, a.y), pk2h(a.z, a.w), pk2h(b.x, b.y), pk2h(b.z, b.w));
    return __builtin_bit_cast(half8, u);
}
static __device__ __forceinline__ int4 cvt8h(float4 a, float4 b, float sc) {
    float4 as = make_float4(a.x * sc, a.y * sc, a.z * sc, a.w * sc);
    float4 bs = make_float4(b.x * sc, b.y * sc, b.z * sc, b.w * sc);
    return __builtin_bit_cast(int4, to_h8(as, bs));
}
static __device__ __forceinline__ float4 ld4(const float* p) {
    return *reinterpret_cast<const float4*>(p);
}
static __device__ __forceinline__ float sel4(floatx4 v, bool r0, bool r1) {
    float lo = r0 ? v[1] : v[0];
    float hi = r0 ? v[3] : v[2];
    return r1 ? hi : lo;
}

__global__ __launch_bounds__(256, 1)
void lstm_mfma_kernel(const float* __restrict__ x,
                      const float* __restrict__ W_ih,
                      const float* __restrict__ W_hh,
                      const float* __restrict__ b_ih,
                      const float* __restrict__ b_hh,
                      const float* __restrict__ W_fc,
                      const float* __restrict__ b_fc,
                      float* __restrict__ out) {
    const int tid   = threadIdx.x;
    const int lane  = tid & 63;
    const int w     = tid >> 6;        // wave -> j-slice [16w, 16w+16)
    const int q     = lane >> 4;       // k-quad / C row group
    const int m     = lane & 15;       // A row-in-tile / B col / C col
    const int b     = m & 1;           // batch within stream (cols = 2b x 8 repl)
    const int rho   = (m >> 1) & 3;    // replica -> C row r to activate
    const bool r0   = (rho & 1) != 0;
    const bool r1   = (rho & 2) != 0;
    const int jmine = 16 * w + 4 * q + rho;
    const bool wr8  = (m < 8);         // one writer per (j,b) per stream
    const int bbase = blockIdx.x * BT;

    __shared__ __align__(16) _Float16 hbuf[2][BT][HSTRIDE];  // h, dbuf by step parity
    __shared__ __align__(16) float hfin[BT][LSTM_H];         // final h for FC

    // ---- weights as pinned fp16 A-fragments, log2e folded ----
    int4 Ah[4][2], Ax[4];
    floatx4 biasC[4];
    #pragma unroll
    for (int tt = 0; tt < 4; ++tt) {
        const float sc = (tt == 2) ? L2E2 : L2E;
        const int gt = tt * 64 + 16 * w + m;
        #pragma unroll
        for (int c = 0; c < 2; ++c) {
            const float* s = W_hh + gt * LSTM_H + 32 * c + 8 * q;
            Ah[tt][c] = cvt8h(ld4(s), ld4(s + 4), sc);
            pin4(Ah[tt][c]);
        }
        float4 xa = make_float4(0.f, 0.f, 0.f, 0.f), xb = xa;
        if (q < 2) {
            const float* s = W_ih + gt * LSTM_IN + 8 * q;
            xa = ld4(s); xb = ld4(s + 4);
        }
        Ax[tt] = cvt8h(xa, xb, sc);
        pin4(Ax[tt]);
        const int gb = tt * 64 + 16 * w + 4 * q;
        float4 bi = ld4(b_ih + gb), bh = ld4(b_hh + gb);
        float4 bs = make_float4((bi.x + bh.x) * sc, (bi.y + bh.y) * sc,
                                (bi.z + bh.z) * sc, (bi.w + bh.w) * sc);
        pinf4(bs);
        biasC[tt] = __builtin_bit_cast(floatx4, bs);
    }

    // ---- zero hbuf[1] (h_{-1}=0; step-0 MFMA reads buf[(0+1)&1]=1) ----
    if (tid < 128) {
        int rr = tid >> 5, jj = tid & 31;
        reinterpret_cast<int*>(&hbuf[1][rr][0])[jj] = 0;
    }

    // ---- x streams: stream s covers batch (2s + b); elements 8q (q<2) ----
    const float* xp0 = x + (size_t)(bbase + 0 + b) * LSTM_T * LSTM_IN + 8 * q;
    const float* xp1 = x + (size_t)(bbase + 2 + b) * LSTM_T * LSTM_IN + 8 * q;
    float4 z4 = make_float4(0.f, 0.f, 0.f, 0.f);
    float4 t00 = z4, t01 = z4, t10 = z4, t11 = z4;       // x_0 temps
    float4 xE00 = z4, xE01 = z4, xO00 = z4, xO01 = z4;   // stream0 even/odd sets
    float4 xE10 = z4, xE11 = z4, xO10 = z4, xO11 = z4;   // stream1
    if (q < 2) {
        t00 = ld4(xp0);  t01 = ld4(xp0 + 4);
        t10 = ld4(xp1);  t11 = ld4(xp1 + 4);
        xE00 = ld4(xp0 + LSTM_IN);      xE01 = ld4(xp0 + LSTM_IN + 4);       // x_1
        xE10 = ld4(xp1 + LSTM_IN);      xE11 = ld4(xp1 + LSTM_IN + 4);
        xO00 = ld4(xp0 + 2 * LSTM_IN);  xO01 = ld4(xp0 + 2 * LSTM_IN + 4);   // x_2
        xO10 = ld4(xp1 + 2 * LSTM_IN);  xO11 = ld4(xp1 + 2 * LSTM_IN + 4);
    }

    // acc init: bias + W_ih . x_0 (both streams)
    floatx4 acc0[4], acc1[4];
    {
        half8 xf0 = to_h8(t00, t01);
        half8 xf1 = to_h8(t10, t11);
        #pragma unroll
        for (int tt = 0; tt < 4; ++tt) {
            acc0[tt] = __builtin_amdgcn_mfma_f32_16x16x32_f16(
                __builtin_bit_cast(half8, Ax[tt]), xf0, biasC[tt], 0, 0, 0);
            acc1[tt] = __builtin_amdgcn_mfma_f32_16x16x32_f16(
                __builtin_bit_cast(half8, Ax[tt]), xf1, biasC[tt], 0, 0, 0);
        }
    }
    float creg0 = 0.f, hreg0 = 0.f, creg1 = 0.f, hreg1 = 0.f;
    __syncthreads();   // hbuf zeros visible

// MFMA stage: stream S step T_ — read h_{T_-1} from buf[(T_+1)&1], 8 h-MFMA.
// Results consumed next round (no wait here).
#define MFMA_S(S, T_, ACC)                                                      \
    {                                                                           \
        const _Float16* cur = &hbuf[((T_) + 1) & 1][0][0];                      \
        half8 f0 = *reinterpret_cast<const half8*>(cur + (2*(S) + b) * HSTRIDE + 8 * q);      \
        half8 f1 = *reinterpret_cast<const half8*>(cur + (2*(S) + b) * HSTRIDE + 32 + 8 * q); \
        _Pragma("unroll")                                                       \
        for (int tt = 0; tt < 4; ++tt)                                          \
            ACC[tt] = __builtin_amdgcn_mfma_f32_16x16x32_f16(                   \
                __builtin_bit_cast(half8, Ah[tt][0]), f0, ACC[tt], 0, 0, 0);    \
        _Pragma("unroll")                                                       \
        for (int tt = 0; tt < 4; ++tt)                                          \
            ACC[tt] = __builtin_amdgcn_mfma_f32_16x16x32_f16(                   \
                __builtin_bit_cast(half8, Ah[tt][1]), f1, ACC[tt], 0, 0, 0);    \
    }

// ACT stage: stream S step T_ — activate acc (filled last round), write h_T
// to buf[T_&1], then re-init acc = bias + W_ih.x_{T_+1} and reload x regs.
#define ACT_S(S, T_, ACC, XP, X0, X1, CREG, HREG)                               \
    {                                                                           \
        _Float16* nxt = &hbuf[(T_) & 1][0][0];                                  \
        float gi = sigm2(sel4(ACC[0], r0, r1));                                 \
        float gf = sigm2(sel4(ACC[1], r0, r1));                                 \
        float gg = tanh2(sel4(ACC[2], r0, r1));                                 \
        float go = sigm2(sel4(ACC[3], r0, r1));                                 \
        CREG = fmaf(gf, CREG, gi * gg);                                         \
        HREG = go * tanh2(CREG * L2E2);                                         \
        if (wr8) nxt[(2*(S) + b) * HSTRIDE + jmine] = (_Float16)HREG;           \
        half8 xf = to_h8(X0, X1);                                               \
        _Pragma("unroll")                                                       \
        for (int tt = 0; tt < 4; ++tt)                                          \
            ACC[tt] = __builtin_amdgcn_mfma_f32_16x16x32_f16(                   \
                __builtin_bit_cast(half8, Ax[tt]), xf, biasC[tt], 0, 0, 0);     \
        if (q < 2 && (T_) + 3 < LSTM_T) {                                       \
            X0 = ld4(XP + (size_t)((T_) + 3) * LSTM_IN);                        \
            X1 = ld4(XP + (size_t)((T_) + 3) * LSTM_IN + 4);                    \
        }                                                                       \
    }

    // prologue round A(0): MFMA s0 step 0 (no act yet)
    MFMA_S(0, 0, acc0)
    lite_barrier();

    // steady state: iterations cover B(t) A(t+1) B(t+1) A(t+2), t even
    for (int t = 0; t < LSTM_T - 2; t += 2) {
        MFMA_S(1, t, acc1)                                   // B(t)
        ACT_S(0, t, acc0, xp0, xE00, xE01, creg0, hreg0)
        lite_barrier();
        MFMA_S(0, t + 1, acc0)                               // A(t+1)
        ACT_S(1, t, acc1, xp1, xE10, xE11, creg1, hreg1)
        lite_barrier();
        MFMA_S(1, t + 1, acc1)                               // B(t+1)
        ACT_S(0, t + 1, acc0, xp0, xO00, xO01, creg0, hreg0)
        lite_barrier();
        MFMA_S(0, t + 2, acc0)                               // A(t+2)
        ACT_S(1, t + 1, acc1, xp1, xO10, xO11, creg1, hreg1)
        lite_barrier();
    }
    // tail: B(510) A(511) B(511) + epilogue act s1 511
    MFMA_S(1, LSTM_T - 2, acc1)
    ACT_S(0, LSTM_T - 2, acc0, xp0, xE00, xE01, creg0, hreg0)
    lite_barrier();
    MFMA_S(0, LSTM_T - 1, acc0)
    ACT_S(1, LSTM_T - 2, acc1, xp1, xE10, xE11, creg1, hreg1)
    lite_barrier();
    MFMA_S(1, LSTM_T - 1, acc1)
    ACT_S(0, LSTM_T - 1, acc0, xp0, xO00, xO01, creg0, hreg0)
    lite_barrier();
    {   // act-only s1 step 511 (no LDS write needed)
        float gi = sigm2(sel4(acc1[0], r0, r1));
        float gf = sigm2(sel4(acc1[1], r0, r1));
        float gg = tanh2(sel4(acc1[2], r0, r1));
        float go = sigm2(sel4(acc1[3], r0, r1));
        creg1 = fmaf(gf, creg1, gi * gg);
        hreg1 = go * tanh2(creg1 * L2E2);
    }
#undef MFMA_S
#undef ACT_S

    // ---- final h (fp32) -> LDS, then FC + sigmoid ----
    if (wr8) {
        hfin[0 + b][jmine] = hreg0;
        hfin[2 + b][jmine] = hreg1;
    }
    __syncthreads();

    if (tid < BT * LSTM_OUT) {
        int bb = tid >> 3, o = tid & 7;
        float s = b_fc[o];
        #pragma unroll
        for (int j4 = 0; j4 < LSTM_H / 4; ++j4) {
            float4 wv = ld4(W_fc + o * LSTM_H + 4 * j4);
            float4 hv = *reinterpret_cast<const float4*>(&hfin[bb][4 * j4]);
            s = fmaf(wv.x, hv.x, s);
            s = fmaf(wv.y, hv.y, s);
            s = fmaf(wv.z, hv.z, s);
            s = fmaf(wv.w, hv.w, s);
        }
        out[(size_t)(bbase + bb) * LSTM_OUT + o] = sigm2(s * L2E);
    }
}

extern "C" void kernel_launch(void* const* d_in, const int* in_sizes, int n_in,
                              void* d_out, int out_size, void* d_ws, size_t ws_size,
                              hipStream_t stream) {
    const float* x    = (const float*)d_in[0];
    const float* W_ih = (const float*)d_in[1];
    const float* W_hh = (const float*)d_in[2];
    const float* b_ih = (const float*)d_in[3];
    const float* b_hh = (const float*)d_in[4];
    const float* W_fc = (const float*)d_in[5];
    const float* b_fc = (const float*)d_in[6];
    float* out = (float*)d_out;

    lstm_mfma_kernel<<<1024 / BT, 256, 0, stream>>>(
        x, W_ih, W_hh, b_ih, b_hh, W_fc, b_fc, out);
}